// Round 2
// baseline (582.361 us; speedup 1.0000x reference)
//
#include <hip/hip_runtime.h>

// VectorQuantizer: inputs [32,256,2048] f32, weight [1024,256] f32
// out0 = quantized [32,256,2048] f32, out1 = argmin indices [65536] (as f32)
//
// Round 2: replicate the REFERENCE's float32 rounding semantics:
//   dist = fp32( fp32(xnorm_t + wnorm_k) - fp32(2*dot) )
// The +||x||^2 (~256) term quantizes distances to ULP ~3e-5, creating exact
// ties that np.argmin resolves to the lowest index (~260 rows). Skipping it
// (round 1) computes the TRUE argmin and mismatches -> absmax 921.
// xnorm/wnorm in f64 (uniform-ULP shifts cancel in argmin); dot in fp32 with
// 4x64-term chunked accumulation (noise ~5e-9, BLAS-comparable).

#define VQ_B   32
#define VQ_D   256
#define VQ_T   2048
#define VQ_K   1024
#define TT     128   // t-tile per block
#define KC     128   // k-chunk per iteration
#define DC     64    // d-chunk staged in LDS

// blocks 0..255: xnorm rows; blocks 256..259: wnorm rows. f64 accumulate.
__global__ void vq_norms_kernel(const float* __restrict__ inp,
                                const float* __restrict__ w,
                                float* __restrict__ wnorm,
                                float* __restrict__ xnorm) {
    const int gid = blockIdx.x * 256 + threadIdx.x;
    if (blockIdx.x < 256) {
        const int n = gid;                 // row = b*2048 + t
        const int b = n >> 11, t = n & 2047;
        const float* p = inp + (size_t)b * VQ_D * VQ_T + t;
        double s = 0.0;
        #pragma unroll 8
        for (int d = 0; d < VQ_D; ++d) {
            float v = p[(size_t)d * VQ_T];   // coalesced across lanes (t contiguous)
            s += (double)v * (double)v;
        }
        xnorm[n] = (float)s;
    } else {
        const int k = gid - 256 * 256;     // 0..1023
        const float4* wr = (const float4*)(w + (size_t)k * VQ_D);
        double s = 0.0;
        for (int i = 0; i < VQ_D / 4; ++i) {
            float4 v = wr[i];
            s += (double)v.x * v.x + (double)v.y * v.y
               + (double)v.z * v.z + (double)v.w * v.w;
        }
        wnorm[k] = (float)s;
    }
}

// 64 KiB LDS -> 2 blocks/CU. Ws transposed with XOR swizzle (col ^= (dd&7)<<2):
// staging writes 2-way (free), float4 compute reads aligned + conflict-free.
__global__ __launch_bounds__(256, 2) void vq_main_kernel(
    const float* __restrict__ inp, const float* __restrict__ w,
    const float* __restrict__ wnorm, const float* __restrict__ xnorm,
    float* __restrict__ outq, float* __restrict__ outi)
{
    __shared__ float smem[2 * DC * TT];    // Xs [64][128] | Ws [64][128]
    float* Xs = smem;
    float* Ws = smem + DC * TT;
    float* red_v = smem;                   // overlay on Xs after compute done
    int*   red_i = (int*)(smem + 16 * TT);

    const int tid = threadIdx.x;
    const int tx  = tid & 15;              // t-group: t = tx*4+i and 64+tx*4+i
    const int ky  = tid >> 4;              // k-group: k = ky*4+j and 64+ky*4+j
    const int b   = blockIdx.x >> 4;       // T/TT = 16 tiles per batch
    const int tt0 = (blockIdx.x & 15) * TT;

    const float* xbase = inp + (size_t)b * VQ_D * VQ_T + tt0;

    // per-thread t rows' xnorm (constant across k chunks)
    float xn[8];
    #pragma unroll
    for (int i = 0; i < 8; ++i) {
        const int tl = (i < 4) ? (tx * 4 + i) : (64 + tx * 4 + (i - 4));
        xn[i] = xnorm[(size_t)b * VQ_T + tt0 + tl];
    }

    float bestv[8];
    int   besti[8];
    #pragma unroll
    for (int i = 0; i < 8; ++i) { bestv[i] = 3.0e38f; besti[i] = 0; }

    for (int k0 = 0; k0 < VQ_K; k0 += KC) {
        float accT[8][8];                  // full-chunk dot
        #pragma unroll
        for (int i = 0; i < 8; ++i)
            #pragma unroll
            for (int j = 0; j < 8; ++j) accT[i][j] = 0.f;

        for (int d0 = 0; d0 < VQ_D; d0 += DC) {
            __syncthreads();
            // ---- stage X tile: Xs[dd][tt] = inp[b][d0+dd][tt0+tt] (coalesced f4)
            {
                const int ttl = (tid & 31) * 4;
                const int dd0 = tid >> 5;
                #pragma unroll
                for (int p = 0; p < 8; ++p) {
                    const int dd = dd0 + p * 8;
                    float4 v = *(const float4*)(xbase + (size_t)(d0 + dd) * VQ_T + ttl);
                    *(float4*)(Xs + dd * TT + ttl) = v;
                }
            }
            // ---- stage W tile transposed: Ws[dd][kk ^ sw(dd)] = w[k0+kk][d0+dd]
            {
                const int kk = tid >> 1;
                #pragma unroll
                for (int p = 0; p < 8; ++p) {
                    const int dd4 = ((tid & 1) << 2) + p * 8;
                    float4 v = *(const float4*)(w + (size_t)(k0 + kk) * VQ_D + d0 + dd4);
                    Ws[(dd4 + 0) * TT + (kk ^ (((dd4 + 0) & 7) << 2))] = v.x;
                    Ws[(dd4 + 1) * TT + (kk ^ (((dd4 + 1) & 7) << 2))] = v.y;
                    Ws[(dd4 + 2) * TT + (kk ^ (((dd4 + 2) & 7) << 2))] = v.z;
                    Ws[(dd4 + 3) * TT + (kk ^ (((dd4 + 3) & 7) << 2))] = v.w;
                }
            }
            __syncthreads();
            // ---- 8x8 outer-product accumulate over DC depth (chunk accumulator
            //      then one add into accT: 4x64 chunked sum, noise ~5e-9)
            float accC[8][8];
            #pragma unroll
            for (int i = 0; i < 8; ++i)
                #pragma unroll
                for (int j = 0; j < 8; ++j) accC[i][j] = 0.f;
            #pragma unroll 4
            for (int dd = 0; dd < DC; ++dd) {
                const int sw = (dd & 7) << 2;
                float4 xa = *(const float4*)(Xs + dd * TT + tx * 4);
                float4 xb = *(const float4*)(Xs + dd * TT + 64 + tx * 4);
                float4 wa = *(const float4*)(Ws + dd * TT + ((ky * 4) ^ sw));
                float4 wb = *(const float4*)(Ws + dd * TT + (((64 + ky * 4)) ^ sw));
                float xv[8] = {xa.x, xa.y, xa.z, xa.w, xb.x, xb.y, xb.z, xb.w};
                float wv[8] = {wa.x, wa.y, wa.z, wa.w, wb.x, wb.y, wb.z, wb.w};
                #pragma unroll
                for (int i = 0; i < 8; ++i)
                    #pragma unroll
                    for (int j = 0; j < 8; ++j)
                        accC[i][j] += xv[i] * wv[j];
            }
            #pragma unroll
            for (int i = 0; i < 8; ++i)
                #pragma unroll
                for (int j = 0; j < 8; ++j) accT[i][j] += accC[i][j];
        }
        // ---- scores, replicating reference fp32 rounding:
        //      s = fp32( fp32(xn + wn) - 2*dot ).  k ascending + strict '<'
        //      => ties resolve to lowest index, matching np.argmin.
        #pragma unroll
        for (int j = 0; j < 8; ++j) {
            const int kl = (j < 4) ? (ky * 4 + j) : (64 + ky * 4 + (j - 4));
            const int kg = k0 + kl;
            const float wn = wnorm[kg];
            #pragma unroll
            for (int i = 0; i < 8; ++i) {
                const float t1 = xn[i] + wn;           // fp32 round at ~256
                const float s  = t1 - 2.f * accT[i][j]; // one more fp32 round
                if (s < bestv[i]) { bestv[i] = s; besti[i] = kg; }
            }
        }
    }

    // ---- cross-thread argmin reduction: 16 ky-threads share each t
    __syncthreads();
    #pragma unroll
    for (int i = 0; i < 8; ++i) {
        const int tl = (i < 4) ? (tx * 4 + i) : (64 + tx * 4 + (i - 4));
        red_v[ky * TT + tl] = bestv[i];
        red_i[ky * TT + tl] = besti[i];
    }
    __syncthreads();
    if (tid < TT) {
        float bv = red_v[tid];
        int   bi = red_i[tid];
        #pragma unroll
        for (int r = 1; r < 16; ++r) {
            const float v  = red_v[r * TT + tid];
            const int   ii = red_i[r * TT + tid];
            if (v < bv || (v == bv && ii < bi)) { bv = v; bi = ii; }
        }
        red_i[tid] = bi;
        outi[(size_t)b * VQ_T + tt0 + tid] = (float)bi;
    }
    __syncthreads();

    // ---- quantized output: outq[b][d][t] = w[best[t]][d]
    {
        const int t  = tid & 127;
        const int dh = tid >> 7;           // d in [dh*128, dh*128+128)
        const int bi = red_i[t];
        const float* wrow = w + (size_t)bi * VQ_D + dh * 128;
        float* obase = outq + ((size_t)b * VQ_D + (size_t)dh * 128) * VQ_T + tt0 + t;
        #pragma unroll 4
        for (int dd = 0; dd < 128; dd += 4) {
            float4 v = *(const float4*)(wrow + dd);
            obase[(size_t)(dd + 0) * VQ_T] = v.x;
            obase[(size_t)(dd + 1) * VQ_T] = v.y;
            obase[(size_t)(dd + 2) * VQ_T] = v.z;
            obase[(size_t)(dd + 3) * VQ_T] = v.w;
        }
    }
}

extern "C" void kernel_launch(void* const* d_in, const int* in_sizes, int n_in,
                              void* d_out, int out_size, void* d_ws, size_t ws_size,
                              hipStream_t stream) {
    const float* inp = (const float*)d_in[0];
    const float* w   = (const float*)d_in[1];
    float* outq  = (float*)d_out;
    float* outi  = outq + (size_t)VQ_B * VQ_D * VQ_T;   // indices appended flat
    float* wnorm = (float*)d_ws;                        // [1024]
    float* xnorm = wnorm + VQ_K;                        // [65536]

    vq_norms_kernel<<<dim3(256 + VQ_K / 256), dim3(256), 0, stream>>>(
        inp, w, wnorm, xnorm);
    vq_main_kernel<<<dim3(VQ_B * (VQ_T / TT)), dim3(256), 0, stream>>>(
        inp, w, wnorm, xnorm, outq, outi);
}

// Round 3
// 329.525 us; speedup vs baseline: 1.7673x; 1.7673x over previous
//
#include <hip/hip_runtime.h>

// VectorQuantizer: inputs [32,256,2048] f32, weight [1024,256] f32
// out0 = quantized [32,256,2048] f32, out1 = argmin indices [65536] (as f32)
//
// Round 3: fp32-accurate distance GEMM via fp16x2-split MFMA (3 products),
// codebook pre-scaled by 1024 (exact), lo-parts scaled by 2^24 into a
// separate accumulator (avoids fp16 denormal flush, keeps error ~1e-8).
// Distance rounding chain replicates the reference exactly (round-2 recipe):
//   s = fp32( fp32(xnorm + wnorm) - fp32(2*dot) ), argmin ties -> lowest k.

#define VQ_B   32
#define VQ_D   256
#define VQ_T   2048
#define VQ_K   1024

typedef _Float16 f16x8 __attribute__((ext_vector_type(8)));
typedef float    f32x4 __attribute__((ext_vector_type(4)));

#define GLOAD_LDS16(gaddr, laddr) \
  __builtin_amdgcn_global_load_lds((const __attribute__((address_space(1))) void*)(gaddr), \
                                   (__attribute__((address_space(3))) void*)(laddr), 16, 0, 0)

// ---------------- kernel 1: norms (f64, UNCHANGED from passing round 2) + W split
__global__ void vq_norms_kernel(const float* __restrict__ inp,
                                const float* __restrict__ w,
                                float* __restrict__ wnorm,
                                float* __restrict__ xnorm,
                                _Float16* __restrict__ Wh,
                                _Float16* __restrict__ Wl) {
    const int gid = blockIdx.x * 256 + threadIdx.x;
    if (blockIdx.x < 256) {
        const int n = gid;                 // row = b*2048 + t
        const int b = n >> 11, t = n & 2047;
        const float* p = inp + (size_t)b * VQ_D * VQ_T + t;
        double s = 0.0;
        #pragma unroll 8
        for (int d = 0; d < VQ_D; ++d) {
            float v = p[(size_t)d * VQ_T];
            s += (double)v * (double)v;
        }
        xnorm[n] = (float)s;
    } else {
        const int k = gid - 256 * 256;     // 0..1023
        const float4* wr = (const float4*)(w + (size_t)k * VQ_D);
        double s = 0.0;
        for (int i = 0; i < VQ_D / 4; ++i) {
            float4 v = wr[i];
            s += (double)v.x * v.x + (double)v.y * v.y
               + (double)v.z * v.z + (double)v.w * v.w;
            const float e4[4] = {v.x, v.y, v.z, v.w};
            #pragma unroll
            for (int j = 0; j < 4; ++j) {
                const float es = e4[j] * 1024.0f;          // exact pow2 scale
                const _Float16 h = (_Float16)es;
                const _Float16 l = (_Float16)((es - (float)h) * 16777216.0f);
                Wh[(size_t)k * VQ_D + i * 4 + j] = h;
                Wl[(size_t)k * VQ_D + i * 4 + j] = l;
            }
        }
        wnorm[k] = (float)s;
    }
}

// ---------------- kernel 2: X transpose + fp16x2 split -> Xh/Xl [65536][256]
__global__ __launch_bounds__(256) void vq_xsplit_kernel(
    const float* __restrict__ inp,
    _Float16* __restrict__ Xh, _Float16* __restrict__ Xl)
{
    __shared__ float xs[64 * 257];         // [d][t], stride 257: reads 2-way free
    const int tid = threadIdx.x;
    const int b   = blockIdx.x & 31;
    const int dt  = (blockIdx.x >> 5) & 3;
    const int tt  = blockIdx.x >> 7;       // 0..7
    const int d0 = dt * 64, t0 = tt * 256;
    const float* src = inp + ((size_t)b * VQ_D + d0) * VQ_T + t0;
    {
        const int c  = tid & 63;           // t chunk of 4 floats (coalesced 1KB/wave)
        const int r0 = tid >> 6;           // 0..3
        #pragma unroll
        for (int p = 0; p < 16; ++p) {
            const int d = r0 * 16 + p;
            float4 v = *(const float4*)(src + (size_t)d * VQ_T + c * 4);
            xs[d * 257 + c * 4 + 0] = v.x;
            xs[d * 257 + c * 4 + 1] = v.y;
            xs[d * 257 + c * 4 + 2] = v.z;
            xs[d * 257 + c * 4 + 3] = v.w;
        }
    }
    __syncthreads();
    {
        const int t = tid;                 // one t-row per thread
        const size_t row = (size_t)b * VQ_T + t0 + t;
        #pragma unroll
        for (int j = 0; j < 8; ++j) {
            f16x8 hv, lv;
            #pragma unroll
            for (int jj = 0; jj < 8; ++jj) {
                const float x = xs[(j * 8 + jj) * 257 + t];
                const _Float16 h = (_Float16)x;
                hv[jj] = h;
                lv[jj] = (_Float16)((x - (float)h) * 16777216.0f);
            }
            *(f16x8*)(Xh + row * VQ_D + d0 + j * 8) = hv;
            *(f16x8*)(Xl + row * VQ_D + d0 + j * 8) = lv;
        }
    }
}

// ---------------- kernel 3: MFMA distance GEMM + argmin + gather
// 512 blocks, 4 waves (2x2), 128t x 128k tile, BK=32, k-chunk loop of 8.
// Staging: global_load_lds(16B) per-lane gather; LDS region order == frag
// order -> conflict-free ds_read_b128, no VALU repack.
__global__ __launch_bounds__(256, 2) void vq_mfma_kernel(
    const _Float16* __restrict__ Wh, const _Float16* __restrict__ Wl,
    const _Float16* __restrict__ Xh, const _Float16* __restrict__ Xl,
    const float* __restrict__ wnorm, const float* __restrict__ xnorm,
    const float* __restrict__ w,
    float* __restrict__ outq, float* __restrict__ outi)
{
    __shared__ alignas(16) char stg[32768];   // 32 regions x 1024 B
    const int tid  = threadIdx.x;
    const int lane = tid & 63;
    const int wv   = tid >> 6;                // wave 0..3
    const int m16  = lane & 15;
    const int quad = lane >> 4;
    const int wm   = wv & 1;                  // k half
    const int wn   = wv >> 1;                 // t half
    const int b    = blockIdx.x >> 4;
    const int tt0  = (blockIdx.x & 15) * 128;
    const long bt  = (long)b * VQ_T + tt0;

    // xnorm for this lane's 4 t-columns (constant across k)
    float xnr[4];
    #pragma unroll
    for (int fn = 0; fn < 4; ++fn)
        xnr[fn] = xnorm[bt + wn * 64 + fn * 16 + m16];

    // 8 staging source pointers per wave: wave0=Wh, wave1=Wl, wave2=Xh, wave3=Xl
    const char* gp[8];
    {
        const char* baseW = (const char*)((wv & 1) ? Wl : Wh);
        const char* baseX = (const char*)((wv & 1) ? Xl : Xh);
        #pragma unroll
        for (int i = 0; i < 8; ++i) {
            const int hf = i >> 2, f = i & 3;
            if (wv < 2) {
                const long row = hf * 64 + f * 16 + m16;        // k row (k0 added by advance)
                gp[i] = baseW + row * 512 + quad * 16;
            } else {
                const long row = bt + hf * 64 + f * 16 + m16;   // t row
                gp[i] = baseX + row * 512 + quad * 16;
            }
        }
    }

    float bestv[4] = {3.0e38f, 3.0e38f, 3.0e38f, 3.0e38f};
    int   besti[4] = {0, 0, 0, 0};

    for (int k0 = 0; k0 < VQ_K; k0 += 128) {
        f32x4 acch[4][4], accl[4][4];
        #pragma unroll
        for (int fm = 0; fm < 4; ++fm)
            #pragma unroll
            for (int fn = 0; fn < 4; ++fn) {
                acch[fm][fn] = (f32x4){0.f, 0.f, 0.f, 0.f};
                accl[fm][fn] = (f32x4){0.f, 0.f, 0.f, 0.f};
            }

        for (int d0 = 0; d0 < VQ_D; d0 += 32) {
            __syncthreads();                  // prior step's LDS reads done
            #pragma unroll
            for (int i = 0; i < 8; ++i) {
                GLOAD_LDS16(gp[i], stg + (wv * 8 + i) * 1024);
                gp[i] += 64;                  // next 32 halves of depth
            }
            __syncthreads();                  // vmcnt drain -> data visible

            f16x8 ah[4], al[4], bh[4], bl[4];
            #pragma unroll
            for (int f = 0; f < 4; ++f) {
                ah[f] = *(const f16x8*)(stg + ((wm * 4 + f)) * 1024 + lane * 16);
                al[f] = *(const f16x8*)(stg + ((8 + wm * 4 + f)) * 1024 + lane * 16);
                bh[f] = *(const f16x8*)(stg + ((16 + wn * 4 + f)) * 1024 + lane * 16);
                bl[f] = *(const f16x8*)(stg + ((24 + wn * 4 + f)) * 1024 + lane * 16);
            }
            #pragma unroll
            for (int fm = 0; fm < 4; ++fm)
                #pragma unroll
                for (int fn = 0; fn < 4; ++fn) {
                    acch[fm][fn] = __builtin_amdgcn_mfma_f32_16x16x32_f16(
                        ah[fm], bh[fn], acch[fm][fn], 0, 0, 0);
                    accl[fm][fn] = __builtin_amdgcn_mfma_f32_16x16x32_f16(
                        ah[fm], bl[fn], accl[fm][fn], 0, 0, 0);
                    accl[fm][fn] = __builtin_amdgcn_mfma_f32_16x16x32_f16(
                        al[fm], bh[fn], accl[fm][fn], 0, 0, 0);
                }
        }
        // advance staging pointers: W -> next k-chunk; X -> rewind depth
        #pragma unroll
        for (int i = 0; i < 8; ++i)
            gp[i] += (wv < 2) ? (128 * 512 - 512) : (-512);

        // scores + running argmin (k ascending; strict '<' => lowest-index ties)
        #pragma unroll
        for (int fm = 0; fm < 4; ++fm) {
            #pragma unroll
            for (int r = 0; r < 4; ++r) {
                const int kg = k0 + wm * 64 + fm * 16 + quad * 4 + r;
                const float wnk = wnorm[kg];
                #pragma unroll
                for (int fn = 0; fn < 4; ++fn) {
                    const float t1 = xnr[fn] + wnk;                     // ref round 1
                    const float d2 = (acch[fm][fn][r]
                                      + accl[fm][fn][r] * 5.9604644775390625e-8f)
                                     * 0.001953125f;                    // = fp32(2*dot)
                    const float s = t1 - d2;                            // ref round 2
                    if (s < bestv[fn]) { bestv[fn] = s; besti[fn] = kg; }
                }
            }
        }
    }

    // cross-lane argmin: lanes {c, c+16, c+32, c+48} share a t-column
    float rv[4]; int ri[4];
    #pragma unroll
    for (int fn = 0; fn < 4; ++fn) {
        float bv = bestv[fn]; int bi = besti[fn];
        #pragma unroll
        for (int mask = 16; mask <= 32; mask <<= 1) {
            const float ov = __shfl_xor(bv, mask, 64);
            const int   oi = __shfl_xor(bi, mask, 64);
            if (ov < bv || (ov == bv && oi < bi)) { bv = ov; bi = oi; }
        }
        rv[fn] = bv; ri[fn] = bi;
    }

    // cross-wave (wm 0 vs 1) reduce via LDS overlay on stg
    __syncthreads();
    float* sv = (float*)stg;              // [2][128]
    int*   si = (int*)(stg + 1024);       // [2][128]
    if (quad == 0) {
        #pragma unroll
        for (int fn = 0; fn < 4; ++fn) {
            const int tl = wn * 64 + fn * 16 + m16;
            sv[wm * 128 + tl] = rv[fn];
            si[wm * 128 + tl] = ri[fn];
        }
    }
    __syncthreads();
    if (tid < 128) {
        const float v0 = sv[tid], v1 = sv[128 + tid];
        const int   i0 = si[tid], i1 = si[128 + tid];
        const int   bi = (v1 < v0 || (v1 == v0 && i1 < i0)) ? i1 : i0;
        si[tid] = bi;
        outi[bt + tid] = (float)bi;
    }
    __syncthreads();

    // quantized output: outq[b][d][t] = w[best[t]][d]  (round-2 verified code)
    {
        const int t  = tid & 127;
        const int dh = tid >> 7;
        const int bi = si[t];
        const float* wrow = w + (size_t)bi * VQ_D + dh * 128;
        float* obase = outq + ((size_t)b * VQ_D + (size_t)dh * 128) * VQ_T + tt0 + t;
        #pragma unroll 4
        for (int dd = 0; dd < 128; dd += 4) {
            float4 v = *(const float4*)(wrow + dd);
            obase[(size_t)(dd + 0) * VQ_T] = v.x;
            obase[(size_t)(dd + 1) * VQ_T] = v.y;
            obase[(size_t)(dd + 2) * VQ_T] = v.z;
            obase[(size_t)(dd + 3) * VQ_T] = v.w;
        }
    }
}

extern "C" void kernel_launch(void* const* d_in, const int* in_sizes, int n_in,
                              void* d_out, int out_size, void* d_ws, size_t ws_size,
                              hipStream_t stream) {
    const float* inp = (const float*)d_in[0];
    const float* w   = (const float*)d_in[1];
    float* outq  = (float*)d_out;
    float* outi  = outq + (size_t)VQ_B * VQ_D * VQ_T;   // indices appended flat

    float*    wnorm = (float*)d_ws;                     // [1024]
    float*    xnorm = wnorm + VQ_K;                     // [65536]
    _Float16* Wh    = (_Float16*)(xnorm + VQ_B * VQ_T); // [1024*256]
    _Float16* Wl    = Wh + (size_t)VQ_K * VQ_D;
    _Float16* Xh    = Wl + (size_t)VQ_K * VQ_D;         // [65536*256]
    _Float16* Xl    = Xh + (size_t)VQ_B * VQ_T * VQ_D;
    // total ws use: ~68.4 MB

    vq_norms_kernel<<<dim3(256 + VQ_K / 256), dim3(256), 0, stream>>>(
        inp, w, wnorm, xnorm, Wh, Wl);
    vq_xsplit_kernel<<<dim3(VQ_B * 4 * 8), dim3(256), 0, stream>>>(inp, Xh, Xl);
    vq_mfma_kernel<<<dim3(VQ_B * (VQ_T / 128)), dim3(256), 0, stream>>>(
        Wh, Wl, Xh, Xl, wnorm, xnorm, w, outq, outi);
}

// Round 4
// 273.608 us; speedup vs baseline: 2.1285x; 1.2044x over previous
//
#include <hip/hip_runtime.h>

// VectorQuantizer: inputs [32,256,2048] f32, weight [1024,256] f32
// out0 = quantized [32,256,2048] f32, out1 = argmin indices [65536] (as f32)
//
// Round 4: (a) double-buffered single-barrier MFMA K-loop (loads for step s+1
// issued right after the barrier of step s -> vmcnt drain overlaps compute);
// (b) fused X-prep (xnorm + fp16x2 split, one pass, no LDS) with X re-laid
// out as [b][dchunk][t][8 halves] so prep writes are contiguous and the main
// kernel's gather pulls 4x256B segments. LDS image and all numerics are
// bit-identical to the verified round-3 kernel:
//   dist = fp32( fp32(xnorm + wnorm) - fp32(2*dot) ),
//   dot = fp16x2-split 3-product MFMA, W pre-scaled by 1024, lo terms * 2^24.

#define VQ_B   32
#define VQ_D   256
#define VQ_T   2048
#define VQ_K   1024

typedef _Float16 f16x8 __attribute__((ext_vector_type(8)));
typedef float    f32x4 __attribute__((ext_vector_type(4)));

#define GLOAD_LDS16(gaddr, laddr) \
  __builtin_amdgcn_global_load_lds((const __attribute__((address_space(1))) void*)(gaddr), \
                                   (__attribute__((address_space(3))) void*)(laddr), 16, 0, 0)

// ---------------- kernel 1: W norms (f64, verified) + fp16x2 split. 4 blocks.
__global__ void vq_wprep_kernel(const float* __restrict__ w,
                                float* __restrict__ wnorm,
                                _Float16* __restrict__ Wh,
                                _Float16* __restrict__ Wl) {
    const int k = blockIdx.x * 256 + threadIdx.x;   // 0..1023
    const float4* wr = (const float4*)(w + (size_t)k * VQ_D);
    double s = 0.0;
    for (int i = 0; i < VQ_D / 4; ++i) {
        float4 v = wr[i];
        s += (double)v.x * v.x + (double)v.y * v.y
           + (double)v.z * v.z + (double)v.w * v.w;
        const float e4[4] = {v.x, v.y, v.z, v.w};
        #pragma unroll
        for (int j = 0; j < 4; ++j) {
            const float es = e4[j] * 1024.0f;          // exact pow2 scale
            const _Float16 h = (_Float16)es;
            const _Float16 l = (_Float16)((es - (float)h) * 16777216.0f);
            Wh[(size_t)k * VQ_D + i * 4 + j] = h;
            Wl[(size_t)k * VQ_D + i * 4 + j] = l;
        }
    }
    wnorm[k] = (float)s;
}

// ---------------- kernel 2: fused X prep: xnorm (f64, same summation order as
// the verified round-2/3 norms kernel) + fp16x2 split, written in chunk layout
// Xh[((b*32 + dc)*2048 + t)*8 + j]  (dc = d/8). No LDS transpose needed:
// reads are lane-coalesced (lanes span t), writes are 1KB-contiguous.
__global__ __launch_bounds__(256) void vq_xprep_kernel(
    const float* __restrict__ inp,
    _Float16* __restrict__ Xh, _Float16* __restrict__ Xl,
    float* __restrict__ xnorm)
{
    __shared__ double ps[128];
    const int tid  = threadIdx.x;
    const int t    = tid & 127;
    const int half = tid >> 7;                 // d half: 0 -> d 0..127, 1 -> 128..255
    const int b    = blockIdx.x >> 4;
    const int tg   = (blockIdx.x & 15) * 128 + t;
    const float* p = inp + (size_t)b * VQ_D * VQ_T + tg;

    double s = 0.0;
    for (int dc = half * 16; dc < half * 16 + 16; ++dc) {
        float x[8];
        #pragma unroll
        for (int j = 0; j < 8; ++j)
            x[j] = p[(size_t)(dc * 8 + j) * VQ_T];     // 256B coalesced per wave
        f16x8 hv, lv;
        #pragma unroll
        for (int j = 0; j < 8; ++j) {
            s += (double)x[j] * (double)x[j];          // sequential-d f64 order
            const _Float16 h = (_Float16)x[j];
            hv[j] = h;
            lv[j] = (_Float16)((x[j] - (float)h) * 16777216.0f);
        }
        const size_t off = (((size_t)b * 32 + dc) * VQ_T + tg) * 8;
        *(f16x8*)(Xh + off) = hv;                      // 1KB contiguous per wave
        *(f16x8*)(Xl + off) = lv;
    }
    if (half) ps[t] = s;
    __syncthreads();
    if (!half) xnorm[(size_t)b * VQ_T + tg] = (float)(s + ps[t]);
}

// ---------------- kernel 3: MFMA distance GEMM + argmin + gather
// 512 blocks, 4 waves (2x2), 128t x 128k tile, 64 linear (k0,d0) steps,
// double-buffered 2x32KB staging, ONE barrier per step: loads for step s+1
// are issued right after the barrier of step s, so the vmcnt(0) drain at the
// next barrier overlaps a full compute phase.
__global__ __launch_bounds__(256, 2) void vq_mfma_kernel(
    const _Float16* __restrict__ Wh, const _Float16* __restrict__ Wl,
    const _Float16* __restrict__ Xh, const _Float16* __restrict__ Xl,
    const float* __restrict__ wnorm, const float* __restrict__ xnorm,
    const float* __restrict__ w,
    float* __restrict__ outq, float* __restrict__ outi)
{
    __shared__ alignas(16) char stg[2][32768];   // 2 x 32 regions x 1024 B
    const int tid  = threadIdx.x;
    const int lane = tid & 63;
    const int wv   = tid >> 6;                // wave 0..3
    const int m16  = lane & 15;
    const int quad = lane >> 4;
    const int wm   = wv & 1;                  // k half (waves 0/1), lo/hi sel
    const int wn   = wv >> 1;                 // t half
    const int b    = blockIdx.x >> 4;
    const int tt0  = (blockIdx.x & 15) * 128;
    const long bt  = (long)b * VQ_T + tt0;

    // xnorm for this lane's 4 t-columns (constant across k)
    float xnr[4];
    #pragma unroll
    for (int fn = 0; fn < 4; ++fn)
        xnr[fn] = xnorm[bt + wn * 64 + fn * 16 + m16];

    // 8 staging source pointers per wave: wave0=Wh, wave1=Wl, wave2=Xh, wave3=Xl
    const char* gp[8];
    #pragma unroll
    for (int i = 0; i < 8; ++i) {
        const int hf = i >> 2, f = i & 3;
        if (wv < 2) {
            const char* baseW = (const char*)((wv & 1) ? Wl : Wh);
            gp[i] = baseW + (size_t)(hf * 64 + f * 16 + m16) * 512 + quad * 16;
        } else {
            const char* baseX = (const char*)((wv & 1) ? Xl : Xh);
            // chunk layout: byte addr = ((b*32 + dc0+quad)*2048 + t_row)*16
            gp[i] = baseX + (((size_t)b * 32 + quad) * 2048
                             + (tt0 + hf * 64 + f * 16 + m16)) * 16;
        }
    }
    // advance after issuing step q: W +64B (32 halves), X +4 dchunks;
    // at chunk boundary W jumps k0+=128 and rewinds d, X rewinds d.
    auto advance = [&](int q) {
        if ((q & 7) == 7) {
            #pragma unroll
            for (int i = 0; i < 8; ++i)
                gp[i] += (wv < 2) ? (long)(65536 - 448) : (long)(-7) * 131072;
        } else {
            #pragma unroll
            for (int i = 0; i < 8; ++i)
                gp[i] += (wv < 2) ? 64L : 131072L;
        }
    };

    float bestv[4] = {3.0e38f, 3.0e38f, 3.0e38f, 3.0e38f};
    int   besti[4] = {0, 0, 0, 0};
    f32x4 acch[4][4], accl[4][4];

    // prologue: issue step 0 into buffer 0
    #pragma unroll
    for (int i = 0; i < 8; ++i)
        GLOAD_LDS16(gp[i], &stg[0][(wv * 8 + i) * 1024]);
    advance(0);

    for (int s = 0; s < 64; ++s) {
        const int cur = s & 1;
        if ((s & 7) == 0) {
            #pragma unroll
            for (int fm = 0; fm < 4; ++fm)
                #pragma unroll
                for (int fn = 0; fn < 4; ++fn) {
                    acch[fm][fn] = (f32x4){0.f, 0.f, 0.f, 0.f};
                    accl[fm][fn] = (f32x4){0.f, 0.f, 0.f, 0.f};
                }
        }
        __syncthreads();            // drains vmcnt -> stg[cur] resident
        if (s < 63) {               // prefetch step s+1 into the other buffer
            #pragma unroll
            for (int i = 0; i < 8; ++i)
                GLOAD_LDS16(gp[i], &stg[cur ^ 1][(wv * 8 + i) * 1024]);
            advance(s + 1);
        }

        const char* base = stg[cur];
        f16x8 ah[4], al[4], bh[4], bl[4];
        #pragma unroll
        for (int f = 0; f < 4; ++f) {
            ah[f] = *(const f16x8*)(base + ((wm * 4 + f)) * 1024 + lane * 16);
            al[f] = *(const f16x8*)(base + ((8 + wm * 4 + f)) * 1024 + lane * 16);
            bh[f] = *(const f16x8*)(base + ((16 + wn * 4 + f)) * 1024 + lane * 16);
            bl[f] = *(const f16x8*)(base + ((24 + wn * 4 + f)) * 1024 + lane * 16);
        }
        #pragma unroll
        for (int fm = 0; fm < 4; ++fm)
            #pragma unroll
            for (int fn = 0; fn < 4; ++fn) {
                acch[fm][fn] = __builtin_amdgcn_mfma_f32_16x16x32_f16(
                    ah[fm], bh[fn], acch[fm][fn], 0, 0, 0);
                accl[fm][fn] = __builtin_amdgcn_mfma_f32_16x16x32_f16(
                    ah[fm], bl[fn], accl[fm][fn], 0, 0, 0);
                accl[fm][fn] = __builtin_amdgcn_mfma_f32_16x16x32_f16(
                    al[fm], bh[fn], accl[fm][fn], 0, 0, 0);
            }

        if ((s & 7) == 7) {
            const int k0 = (s >> 3) * 128;
            // scores, reference fp32 rounding chain; strict '<' over ascending
            // k => ties resolve to lowest index (matches np.argmin)
            #pragma unroll
            for (int fm = 0; fm < 4; ++fm) {
                #pragma unroll
                for (int r = 0; r < 4; ++r) {
                    const int kg = k0 + wm * 64 + fm * 16 + quad * 4 + r;
                    const float wnk = wnorm[kg];
                    #pragma unroll
                    for (int fn = 0; fn < 4; ++fn) {
                        const float t1 = xnr[fn] + wnk;
                        const float d2 = (acch[fm][fn][r]
                                          + accl[fm][fn][r] * 5.9604644775390625e-8f)
                                         * 0.001953125f;
                        const float sc = t1 - d2;
                        if (sc < bestv[fn]) { bestv[fn] = sc; besti[fn] = kg; }
                    }
                }
            }
        }
    }

    // cross-lane argmin: lanes {c, c+16, c+32, c+48} share a t-column
    float rv[4]; int ri[4];
    #pragma unroll
    for (int fn = 0; fn < 4; ++fn) {
        float bv = bestv[fn]; int bi = besti[fn];
        #pragma unroll
        for (int mask = 16; mask <= 32; mask <<= 1) {
            const float ov = __shfl_xor(bv, mask, 64);
            const int   oi = __shfl_xor(bi, mask, 64);
            if (ov < bv || (ov == bv && oi < bi)) { bv = ov; bi = oi; }
        }
        rv[fn] = bv; ri[fn] = bi;
    }

    // cross-wave (wm 0 vs 1) reduce via LDS overlay
    __syncthreads();
    float* sv = (float*)stg[0];              // [2][128]
    int*   si = (int*)(stg[0] + 1024);       // [2][128]
    if (quad == 0) {
        #pragma unroll
        for (int fn = 0; fn < 4; ++fn) {
            const int tl = wn * 64 + fn * 16 + m16;
            sv[wm * 128 + tl] = rv[fn];
            si[wm * 128 + tl] = ri[fn];
        }
    }
    __syncthreads();
    if (tid < 128) {
        const float v0 = sv[tid], v1 = sv[128 + tid];
        const int   i0 = si[tid], i1 = si[128 + tid];
        const int   bi = (v1 < v0 || (v1 == v0 && i1 < i0)) ? i1 : i0;
        si[tid] = bi;
        outi[bt + tid] = (float)bi;
    }
    __syncthreads();

    // quantized output: outq[b][d][t] = w[best[t]][d]  (verified epilogue)
    {
        const int t  = tid & 127;
        const int dh = tid >> 7;
        const int bi = si[t];
        const float* wrow = w + (size_t)bi * VQ_D + dh * 128;
        float* obase = outq + ((size_t)b * VQ_D + (size_t)dh * 128) * VQ_T + tt0 + t;
        #pragma unroll 4
        for (int dd = 0; dd < 128; dd += 4) {
            float4 v = *(const float4*)(wrow + dd);
            obase[(size_t)(dd + 0) * VQ_T] = v.x;
            obase[(size_t)(dd + 1) * VQ_T] = v.y;
            obase[(size_t)(dd + 2) * VQ_T] = v.z;
            obase[(size_t)(dd + 3) * VQ_T] = v.w;
        }
    }
}

extern "C" void kernel_launch(void* const* d_in, const int* in_sizes, int n_in,
                              void* d_out, int out_size, void* d_ws, size_t ws_size,
                              hipStream_t stream) {
    const float* inp = (const float*)d_in[0];
    const float* w   = (const float*)d_in[1];
    float* outq  = (float*)d_out;
    float* outi  = outq + (size_t)VQ_B * VQ_D * VQ_T;   // indices appended flat

    float*    wnorm = (float*)d_ws;                     // [1024]
    float*    xnorm = wnorm + VQ_K;                     // [65536]
    _Float16* Wh    = (_Float16*)(xnorm + VQ_B * VQ_T); // [1024*256]
    _Float16* Wl    = Wh + (size_t)VQ_K * VQ_D;
    _Float16* Xh    = Wl + (size_t)VQ_K * VQ_D;         // [65536*256], chunk layout
    _Float16* Xl    = Xh + (size_t)VQ_B * VQ_T * VQ_D;
    // total ws use: ~68.4 MB

    vq_wprep_kernel<<<dim3(VQ_K / 256), dim3(256), 0, stream>>>(w, wnorm, Wh, Wl);
    vq_xprep_kernel<<<dim3(VQ_B * (VQ_T / 128)), dim3(256), 0, stream>>>(
        inp, Xh, Xl, xnorm);
    vq_mfma_kernel<<<dim3(VQ_B * (VQ_T / 128)), dim3(256), 0, stream>>>(
        Wh, Wl, Xh, Xl, wnorm, xnorm, w, outq, outi);
}